// Round 1
// baseline (2605.194 us; speedup 1.0000x reference)
//
#include <hip/hip_runtime.h>
#include <hip/hip_bf16.h>
#include <math.h>

#define BQ 32
#define SQ 256
#define MTOK 8192       // B*S
#define DD 128
#define II 256
#define NNs 16
#define RRs 8
#define KKs 4
#define LLs 4
#define ZZs 128
#define FUTs 20

__device__ __forceinline__ float geluf(float x){ return 0.5f*x*(1.0f+erff(x*0.70710678118654752f)); }
__device__ __forceinline__ float siluf(float x){ return x/(1.0f+__expf(-x)); }
__device__ __forceinline__ float softplusf(float x){ return fmaxf(x,0.0f)+log1pf(__expf(-fabsf(x))); }

// ---------------------------------------------------------------------------
// Generic fp32 register-tiled GEMM: C[M,N] = act(A[M,K] @ B[K,N] + bias) (+C)
// A row stride lda, B row stride = N, C row stride ldc.
// 256 threads; thread (trow=tid/16, tcol=tid%16) computes SRxSC quadrants of
// 4x4 (quadrant stride 64) so LDS B reads are <=2-way bank aliased (free).
// Requires: M%BM==0, N%BN==0, K%16==0, lda%4==0.
// ---------------------------------------------------------------------------
template<int BM,int BN,int ACT,int ADD>
__launch_bounds__(256)
__global__ void gemm_kernel(const float* __restrict__ A, const float* __restrict__ B,
                            const float* __restrict__ bias, float* __restrict__ C,
                            int M, int N, int Kd, int lda, int ldc)
{
    constexpr int BK = 16;
    constexpr int SR = BM/64, SC = BN/64;
    __shared__ float As[BK][BM+4];
    __shared__ float Bs[BK][BN+4];
    const int tid  = threadIdx.x;
    const int tcol = tid & 15, trow = tid >> 4;
    const int rowBase = blockIdx.y * BM, colBase = blockIdx.x * BN;

    float acc[SR][SC][4][4];
    #pragma unroll
    for (int r=0;r<SR;r++)
      #pragma unroll
      for (int c=0;c<SC;c++)
        #pragma unroll
        for (int i=0;i<4;i++)
          #pragma unroll
          for (int j=0;j<4;j++) acc[r][c][i][j] = 0.0f;

    constexpr int A4 = BM*BK/1024;   // float4 A loads per thread
    constexpr int B4 = BN*BK/1024;   // float4 B loads per thread

    for (int kt=0; kt<Kd; kt+=BK) {
        #pragma unroll
        for (int e=0;e<A4;e++){
            int idx4 = tid + e*256;
            int row = idx4 >> 2, kg = idx4 & 3;            // 4 k-groups per row
            float4 v = *reinterpret_cast<const float4*>(A + (size_t)(rowBase+row)*lda + kt + kg*4);
            As[kg*4+0][row]=v.x; As[kg*4+1][row]=v.y; As[kg*4+2][row]=v.z; As[kg*4+3][row]=v.w;
        }
        #pragma unroll
        for (int e=0;e<B4;e++){
            int idx4 = tid + e*256;
            int row = idx4 / (BN/4), cg = idx4 % (BN/4);
            float4 v = *reinterpret_cast<const float4*>(B + (size_t)(kt+row)*N + colBase + cg*4);
            *reinterpret_cast<float4*>(&Bs[row][cg*4]) = v;
        }
        __syncthreads();
        #pragma unroll
        for (int kk=0;kk<BK;kk++){
            float4 av[SR], bv[SC];
            #pragma unroll
            for (int r=0;r<SR;r++) av[r] = *reinterpret_cast<const float4*>(&As[kk][trow*4 + r*64]);
            #pragma unroll
            for (int c=0;c<SC;c++) bv[c] = *reinterpret_cast<const float4*>(&Bs[kk][tcol*4 + c*64]);
            #pragma unroll
            for (int r=0;r<SR;r++){
                const float a0=av[r].x, a1=av[r].y, a2=av[r].z, a3=av[r].w;
                #pragma unroll
                for (int c=0;c<SC;c++){
                    const float b0=bv[c].x, b1=bv[c].y, b2=bv[c].z, b3=bv[c].w;
                    acc[r][c][0][0]+=a0*b0; acc[r][c][0][1]+=a0*b1; acc[r][c][0][2]+=a0*b2; acc[r][c][0][3]+=a0*b3;
                    acc[r][c][1][0]+=a1*b0; acc[r][c][1][1]+=a1*b1; acc[r][c][1][2]+=a1*b2; acc[r][c][1][3]+=a1*b3;
                    acc[r][c][2][0]+=a2*b0; acc[r][c][2][1]+=a2*b1; acc[r][c][2][2]+=a2*b2; acc[r][c][2][3]+=a2*b3;
                    acc[r][c][3][0]+=a3*b0; acc[r][c][3][1]+=a3*b1; acc[r][c][3][2]+=a3*b2; acc[r][c][3][3]+=a3*b3;
                }
            }
        }
        __syncthreads();
    }

    // epilogue
    #pragma unroll
    for (int r=0;r<SR;r++){
        #pragma unroll
        for (int i=0;i<4;i++){
            int row = rowBase + trow*4 + r*64 + i;
            #pragma unroll
            for (int c=0;c<SC;c++){
                int col = colBase + tcol*4 + c*64;
                float4 v;
                v.x = acc[r][c][i][0]; v.y = acc[r][c][i][1]; v.z = acc[r][c][i][2]; v.w = acc[r][c][i][3];
                if (bias){
                    float4 bb = *reinterpret_cast<const float4*>(bias + col);
                    v.x += bb.x; v.y += bb.y; v.z += bb.z; v.w += bb.w;
                }
                if (ACT==1){ v.x=geluf(v.x); v.y=geluf(v.y); v.z=geluf(v.z); v.w=geluf(v.w); }
                float* cp = C + (size_t)row*ldc + col;
                if (ADD){
                    float4 old = *reinterpret_cast<const float4*>(cp);
                    v.x += old.x; v.y += old.y; v.z += old.z; v.w += old.w;
                }
                *reinterpret_cast<float4*>(cp) = v;
            }
        }
    }
}

// ---------------------------------------------------------------------------
// RMSNorm: one wave per token (D=128, 2 elems/lane)
// ---------------------------------------------------------------------------
__launch_bounds__(256)
__global__ void rms_kernel(const float* __restrict__ x, const float* __restrict__ w,
                           float* __restrict__ out)
{
    int tid = threadIdx.x;
    int lane = tid & 63, wv = tid >> 6;
    int token = blockIdx.x*4 + wv;
    const float* xr = x + (size_t)token*DD;
    float v0 = xr[lane], v1 = xr[lane+64];
    float ss = v0*v0 + v1*v1;
    #pragma unroll
    for (int off=32; off>0; off>>=1) ss += __shfl_xor(ss, off);
    float r = rsqrtf(ss*(1.0f/DD) + 1e-5f);
    float* o = out + (size_t)token*DD;
    o[lane]    = v0*r*w[lane];
    o[lane+64] = v1*r*w[lane+64];
}

// ---------------------------------------------------------------------------
// Depthwise causal conv (K=4) + bias + silu. Thread per (m,i).
// hg layout (MTOK, 2I); h = first I cols. Output hc (MTOK, I).
// ---------------------------------------------------------------------------
__launch_bounds__(256)
__global__ void conv_kernel(const float* __restrict__ hg, const float* __restrict__ cw,
                            const float* __restrict__ cb, float* __restrict__ hc)
{
    int idx = blockIdx.x*256 + threadIdx.x;
    int i = idx & (II-1);
    int m = idx >> 8;
    int s = m & (SQ-1);
    const float* w = cw + i*KKs;
    float a = cb[i];
    #pragma unroll
    for (int k=0;k<KKs;k++){
        int ssrc = s + k - (KKs-1);
        if (ssrc >= 0) a += hg[(size_t)(m + k - (KKs-1))*(2*II) + i] * w[k];
    }
    hc[idx] = siluf(a);
}

// ---------------------------------------------------------------------------
// Per-token x_proj (I->40) then dt_proj (8->I) + softplus; stores dt and Bm/Cm.
// Block = 64 threads, grid = MTOK.
// ---------------------------------------------------------------------------
__launch_bounds__(64)
__global__ void xproj_dt_kernel(const float* __restrict__ hconv, const float* __restrict__ xpw,
                                const float* __restrict__ dtw, const float* __restrict__ dtbv,
                                float* __restrict__ dt_out, float* __restrict__ bc)
{
    __shared__ float hrow[II];
    __shared__ float ssm[RRs + 2*NNs];   // 40
    int m = blockIdx.x, tid = threadIdx.x;
    for (int t=tid; t<II; t+=64) hrow[t] = hconv[(size_t)m*II + t];
    __syncthreads();
    if (tid < 40){
        float a = 0.0f;
        for (int k=0;k<II;k++) a += hrow[k]*xpw[k*40 + tid];
        ssm[tid] = a;
    }
    __syncthreads();
    if (tid < 32) bc[(size_t)m*32 + tid] = ssm[8 + tid];
    for (int ii=tid; ii<II; ii+=64){
        float a = dtbv[ii];
        #pragma unroll
        for (int r=0;r<RRs;r++) a += ssm[r]*dtw[r*II + ii];
        dt_out[(size_t)m*II + ii] = softplusf(a);
    }
}

// ---------------------------------------------------------------------------
// Selective scan. Grid = B * 8 (i-chunks of 32), block = 64 threads:
// lane = (i_local in [0,32), nh in {0,1}); each thread holds 8 n-states.
// Emits y = (scan + h*D) * silu(gate).
// ---------------------------------------------------------------------------
__launch_bounds__(64)
__global__ void scan_kernel(const float* __restrict__ dtp, const float* __restrict__ bc,
                            const float* __restrict__ hconv, const float* __restrict__ hg,
                            const float* __restrict__ A_log, const float* __restrict__ D_par,
                            float* __restrict__ y)
{
    int b = blockIdx.x >> 3, chunk = blockIdx.x & 7;
    int tid = threadIdx.x;
    int il = tid & 31, nh = tid >> 5;
    int i = chunk*32 + il;
    const float* al = A_log + i*NNs + nh*8;
    float A2[8];
    #pragma unroll
    for (int j=0;j<8;j++) A2[j] = -__expf(al[j]) * 1.44269504f;  // A*log2(e)
    float carry[8];
    #pragma unroll
    for (int j=0;j<8;j++) carry[j]=0.0f;
    const float dpi = D_par[i];
    const int m0 = b*SQ;
    for (int s=0; s<SQ; s++){
        int m = m0 + s;
        float dtv = dtp[(size_t)m*II + i];
        float hv  = hconv[(size_t)m*II + i];
        float gv  = hg[(size_t)m*(2*II) + II + i];
        const float4* bcrow = reinterpret_cast<const float4*>(bc + (size_t)m*32);
        float4 b0 = bcrow[nh*2],   b1 = bcrow[nh*2+1];
        float4 c0 = bcrow[4+nh*2], c1 = bcrow[5+nh*2];
        float Bm[8] = {b0.x,b0.y,b0.z,b0.w,b1.x,b1.y,b1.z,b1.w};
        float Cm[8] = {c0.x,c0.y,c0.z,c0.w,c1.x,c1.y,c1.z,c1.w};
        float du = dtv*hv;
        float acc = 0.0f;
        #pragma unroll
        for (int j=0;j<8;j++){
            float dA = exp2f(dtv*A2[j]);
            carry[j] = carry[j]*dA + du*Bm[j];
            acc += carry[j]*Cm[j];
        }
        acc += __shfl_xor(acc, 32);
        if (nh == 0){
            float yv = (acc + hv*dpi) * siluf(gv);
            y[(size_t)m*II + i] = yv;
        }
    }
}

// ---------------------------------------------------------------------------
// Head: per-batch block (128 threads): final RMS on last token, mu/lv, VIB z,
// KL partial (atomicAdd), MLP head -> d_out[b*40 .. +39].
// ---------------------------------------------------------------------------
__launch_bounds__(128)
__global__ void head_kernel(const float* __restrict__ x, const float* __restrict__ normf,
                            const float* __restrict__ mu_w, const float* __restrict__ mu_b,
                            const float* __restrict__ lv_w, const float* __restrict__ lv_b,
                            const float* __restrict__ eps, const float* __restrict__ h1_w,
                            const float* __restrict__ h1_b, const float* __restrict__ h2_w,
                            const float* __restrict__ h2_b, float* __restrict__ out,
                            float* __restrict__ klacc)
{
    __shared__ float lasts[DD];
    __shared__ float zs[DD];
    __shared__ float hr[256];
    __shared__ float red[2];
    int b = blockIdx.x, d = threadIdx.x;
    int lane = d & 63, wv = d >> 6;
    float xv = x[((size_t)(b*SQ + SQ-1))*DD + d];
    float ss = xv*xv;
    #pragma unroll
    for (int off=32; off>0; off>>=1) ss += __shfl_xor(ss, off);
    if (lane==0) red[wv] = ss;
    __syncthreads();
    float tot = red[0] + red[1];
    float last = xv * rsqrtf(tot*(1.0f/DD) + 1e-5f) * normf[d];
    lasts[d] = last;
    __syncthreads();
    float mu = mu_b[d], lv = lv_b[d];
    for (int j=0;j<DD;j++){
        float lj = lasts[j];
        mu += lj*mu_w[j*DD + d];
        lv += lj*lv_w[j*DD + d];
    }
    float z = mu + eps[b*ZZs + d]*__expf(0.5f*lv);
    zs[d] = z;
    float klp = 1.0f + lv - mu*mu - __expf(lv);
    #pragma unroll
    for (int off=32; off>0; off>>=1) klp += __shfl_xor(klp, off);
    if (lane==0) red[wv] = klp;
    __syncthreads();
    if (d==0) atomicAdd(klacc, red[0]+red[1]);
    // h1: 256 outputs
    for (int o=d; o<256; o+=128){
        float a = h1_b[o];
        for (int j=0;j<DD;j++) a += zs[j]*h1_w[j*256 + o];
        hr[o] = fmaxf(a, 0.0f);
    }
    __syncthreads();
    if (d < 40){
        float a = h2_b[d];
        for (int k=0;k<256;k++) a += hr[k]*h2_w[k*40 + d];
        out[b*(FUTs*2) + d] = a;
    }
}

__global__ void kl_final_kernel(const float* __restrict__ klacc, float* __restrict__ out)
{
    out[0] = -0.5f * klacc[0] * (1.0f/(BQ*ZZs));
}

// ---------------------------------------------------------------------------
extern "C" void kernel_launch(void* const* d_in, const int* in_sizes, int n_in,
                              void* d_out, int out_size, void* d_ws, size_t ws_size,
                              hipStream_t stream)
{
    const float* x_cam     = (const float*)d_in[0];
    const float* x_ego     = (const float*)d_in[1];
    const float* vib_eps   = (const float*)d_in[2];
    const float* vis_w1    = (const float*)d_in[3];
    const float* vis_b1    = (const float*)d_in[4];
    const float* vis_w2    = (const float*)d_in[5];
    const float* vis_b2    = (const float*)d_in[6];
    const float* ego_w     = (const float*)d_in[7];
    const float* ego_b     = (const float*)d_in[8];
    const float* fus_w     = (const float*)d_in[9];
    const float* fus_b     = (const float*)d_in[10];
    const float* norm_w    = (const float*)d_in[11];
    const float* in_proj_w = (const float*)d_in[12];
    const float* conv_w    = (const float*)d_in[13];
    const float* conv_b    = (const float*)d_in[14];
    const float* x_proj_w  = (const float*)d_in[15];
    const float* dt_proj_w = (const float*)d_in[16];
    const float* dt_proj_b = (const float*)d_in[17];
    const float* A_log     = (const float*)d_in[18];
    const float* D_par     = (const float*)d_in[19];
    const float* out_proj_w= (const float*)d_in[20];
    const float* normf_w   = (const float*)d_in[21];
    const float* mu_w      = (const float*)d_in[22];
    const float* mu_b      = (const float*)d_in[23];
    const float* lv_w      = (const float*)d_in[24];
    const float* lv_b      = (const float*)d_in[25];
    const float* h1_w      = (const float*)d_in[26];
    const float* h1_b      = (const float*)d_in[27];
    const float* h2_w      = (const float*)d_in[28];
    const float* h2_b      = (const float*)d_in[29];

    float* ws = (float*)d_ws;
    // buffer layout (floats), with aliasing:
    float* v1g   = ws;                       // 8192*512  (aliases hg)
    float* hg    = ws;
    float* cat   = ws + 4194304;             // 8192*256  (aliases hconv)
    float* hconv = cat;
    float* xbuf  = cat  + 2097152;           // 8192*128
    float* xn    = xbuf + 1048576;           // 8192*128
    float* dtws  = xn   + 1048576;           // 8192*256
    float* bcws  = dtws + 2097152;           // 8192*32
    float* ybuf  = bcws + 262144;            // 8192*256
    float* klacc = ybuf + 2097152;           // 1

    hipMemsetAsync(klacc, 0, sizeof(float), stream);

    // 1) vision GEMM1: gelu(x_cam @ vis_w1 + b1) -> v1g  (8192x512, K=8192)
    gemm_kernel<128,128,1,0><<<dim3(512/128, 8192/128), 256, 0, stream>>>(
        x_cam, vis_w1, vis_b1, v1g, MTOK, 512, 8192, 8192, 512);
    // 2) v2 = v1g @ vis_w2 + b2 -> cat[:, :128]
    gemm_kernel<64,64,0,0><<<dim3(2, 128), 256, 0, stream>>>(
        v1g, vis_w2, vis_b2, cat, MTOK, 128, 512, 512, 256);
    // 3) e = x_ego @ ego_w + b -> cat[:, 128:]
    gemm_kernel<64,64,0,0><<<dim3(2, 128), 256, 0, stream>>>(
        x_ego, ego_w, ego_b, cat + 128, MTOK, 128, 64, 64, 256);
    // 4) fused = gelu(cat @ fus_w + fus_b) -> xbuf
    gemm_kernel<64,64,1,0><<<dim3(2, 128), 256, 0, stream>>>(
        cat, fus_w, fus_b, xbuf, MTOK, 128, 256, 256, 128);

    for (int l=0; l<LLs; l++){
        rms_kernel<<<MTOK/4, 256, 0, stream>>>(xbuf, norm_w + l*DD, xn);
        gemm_kernel<128,128,0,0><<<dim3(512/128, 8192/128), 256, 0, stream>>>(
            xn, in_proj_w + (size_t)l*DD*2*II, nullptr, hg, MTOK, 2*II, DD, DD, 2*II);
        conv_kernel<<<MTOK*II/256, 256, 0, stream>>>(
            hg, conv_w + (size_t)l*II*KKs, conv_b + (size_t)l*II, hconv);
        xproj_dt_kernel<<<MTOK, 64, 0, stream>>>(
            hconv, x_proj_w + (size_t)l*II*40, dt_proj_w + (size_t)l*RRs*II,
            dt_proj_b + (size_t)l*II, dtws, bcws);
        scan_kernel<<<BQ*8, 64, 0, stream>>>(
            dtws, bcws, hconv, hg, A_log + (size_t)l*II*NNs, D_par + (size_t)l*II, ybuf);
        gemm_kernel<64,64,0,1><<<dim3(2, 128), 256, 0, stream>>>(
            ybuf, out_proj_w + (size_t)l*II*DD, nullptr, xbuf, MTOK, DD, II, II, DD);
    }

    head_kernel<<<BQ, 128, 0, stream>>>(
        xbuf, normf_w, mu_w, mu_b, lv_w, lv_b, vib_eps,
        h1_w, h1_b, h2_w, h2_b, (float*)d_out, klacc);
    kl_final_kernel<<<1, 1, 0, stream>>>(klacc, (float*)d_out + 1280);
}

// Round 2
// 1958.254 us; speedup vs baseline: 1.3304x; 1.3304x over previous
//
#include <hip/hip_runtime.h>
#include <hip/hip_bf16.h>
#include <math.h>

#define BQ 32
#define SQ 256
#define MTOK 8192       // B*S
#define DD 128
#define II 256
#define NNs 16
#define RRs 8
#define KKs 4
#define LLs 4
#define ZZs 128
#define FUTs 20

typedef __attribute__((ext_vector_type(8))) short bf8v;   // 8 bf16 (4 VGPRs)
typedef __attribute__((ext_vector_type(4))) float f4v;    // 4 fp32 acc

__device__ __forceinline__ float geluf(float x){ return 0.5f*x*(1.0f+erff(x*0.70710678118654752f)); }
__device__ __forceinline__ float siluf(float x){ return x/(1.0f+__expf(-x)); }
__device__ __forceinline__ float softplusf(float x){ return fmaxf(x,0.0f)+log1pf(__expf(-fabsf(x))); }
__device__ __forceinline__ unsigned short f2bf(float x){
    __hip_bfloat16 h = __float2bfloat16(x);
    return *reinterpret_cast<unsigned short*>(&h);
}

// ---------------------------------------------------------------------------
// fp32 register-tiled GEMM (round-1), used for the small GEMMs + fallback.
// ---------------------------------------------------------------------------
template<int BM,int BN,int ACT,int ADD>
__launch_bounds__(256)
__global__ void gemm_kernel(const float* __restrict__ A, const float* __restrict__ B,
                            const float* __restrict__ bias, float* __restrict__ C,
                            int M, int N, int Kd, int lda, int ldc)
{
    constexpr int BK = 16;
    constexpr int SR = BM/64, SC = BN/64;
    __shared__ float As[BK][BM+4];
    __shared__ float Bs[BK][BN+4];
    const int tid  = threadIdx.x;
    const int tcol = tid & 15, trow = tid >> 4;
    const int rowBase = blockIdx.y * BM, colBase = blockIdx.x * BN;

    float acc[SR][SC][4][4];
    #pragma unroll
    for (int r=0;r<SR;r++)
      #pragma unroll
      for (int c=0;c<SC;c++)
        #pragma unroll
        for (int i=0;i<4;i++)
          #pragma unroll
          for (int j=0;j<4;j++) acc[r][c][i][j] = 0.0f;

    constexpr int A4 = BM*BK/1024;
    constexpr int B4 = BN*BK/1024;

    for (int kt=0; kt<Kd; kt+=BK) {
        #pragma unroll
        for (int e=0;e<A4;e++){
            int idx4 = tid + e*256;
            int row = idx4 >> 2, kg = idx4 & 3;
            float4 v = *reinterpret_cast<const float4*>(A + (size_t)(rowBase+row)*lda + kt + kg*4);
            As[kg*4+0][row]=v.x; As[kg*4+1][row]=v.y; As[kg*4+2][row]=v.z; As[kg*4+3][row]=v.w;
        }
        #pragma unroll
        for (int e=0;e<B4;e++){
            int idx4 = tid + e*256;
            int row = idx4 / (BN/4), cg = idx4 % (BN/4);
            float4 v = *reinterpret_cast<const float4*>(B + (size_t)(kt+row)*N + colBase + cg*4);
            *reinterpret_cast<float4*>(&Bs[row][cg*4]) = v;
        }
        __syncthreads();
        #pragma unroll
        for (int kk=0;kk<BK;kk++){
            float4 av[SR], bv[SC];
            #pragma unroll
            for (int r=0;r<SR;r++) av[r] = *reinterpret_cast<const float4*>(&As[kk][trow*4 + r*64]);
            #pragma unroll
            for (int c=0;c<SC;c++) bv[c] = *reinterpret_cast<const float4*>(&Bs[kk][tcol*4 + c*64]);
            #pragma unroll
            for (int r=0;r<SR;r++){
                const float a0=av[r].x, a1=av[r].y, a2=av[r].z, a3=av[r].w;
                #pragma unroll
                for (int c=0;c<SC;c++){
                    const float b0=bv[c].x, b1=bv[c].y, b2=bv[c].z, b3=bv[c].w;
                    acc[r][c][0][0]+=a0*b0; acc[r][c][0][1]+=a0*b1; acc[r][c][0][2]+=a0*b2; acc[r][c][0][3]+=a0*b3;
                    acc[r][c][1][0]+=a1*b0; acc[r][c][1][1]+=a1*b1; acc[r][c][1][2]+=a1*b2; acc[r][c][1][3]+=a1*b3;
                    acc[r][c][2][0]+=a2*b0; acc[r][c][2][1]+=a2*b1; acc[r][c][2][2]+=a2*b2; acc[r][c][2][3]+=a2*b3;
                    acc[r][c][3][0]+=a3*b0; acc[r][c][3][1]+=a3*b1; acc[r][c][3][2]+=a3*b2; acc[r][c][3][3]+=a3*b3;
                }
            }
        }
        __syncthreads();
    }

    #pragma unroll
    for (int r=0;r<SR;r++){
        #pragma unroll
        for (int i=0;i<4;i++){
            int row = rowBase + trow*4 + r*64 + i;
            #pragma unroll
            for (int c=0;c<SC;c++){
                int col = colBase + tcol*4 + c*64;
                float4 v;
                v.x = acc[r][c][i][0]; v.y = acc[r][c][i][1]; v.z = acc[r][c][i][2]; v.w = acc[r][c][i][3];
                if (bias){
                    float4 bb = *reinterpret_cast<const float4*>(bias + col);
                    v.x += bb.x; v.y += bb.y; v.z += bb.z; v.w += bb.w;
                }
                if (ACT==1){ v.x=geluf(v.x); v.y=geluf(v.y); v.z=geluf(v.z); v.w=geluf(v.w); }
                float* cp = C + (size_t)row*ldc + col;
                if (ADD){
                    float4 old = *reinterpret_cast<const float4*>(cp);
                    v.x += old.x; v.y += old.y; v.z += old.z; v.w += old.w;
                }
                *reinterpret_cast<float4*>(cp) = v;
            }
        }
    }
}

// ---------------------------------------------------------------------------
// bf16 MFMA GEMM: C[M,N] = act(A[M,K]_bf16 @ Bt[N,K]_bf16^T + bias)
// BM=128, BN=64, BK=64. 4 waves; wave w covers rows w*32..+32 (2 m-tiles) x
// all 64 cols (4 n-tiles) of 16x16x32 MFMAs. LDS rows padded to 72 bf16.
// Requires M%128==0, N%64==0, K%64==0.
// ---------------------------------------------------------------------------
template<int ACT>
__launch_bounds__(256,2)
__global__ void gemm_bf16_kernel(const unsigned short* __restrict__ A,
                                 const unsigned short* __restrict__ Bt,
                                 const float* __restrict__ bias,
                                 float* __restrict__ C,
                                 int M, int N, int Kd)
{
    constexpr int LDK = 72;
    __shared__ unsigned short As[128*LDK];
    __shared__ unsigned short Bs[64*LDK];
    const int tid = threadIdx.x;
    const int w = tid >> 6, lane = tid & 63;
    const int ml = lane & 15, quad = lane >> 4;
    const int rowBase = blockIdx.y * 128, colBase = blockIdx.x * 64;

    f4v acc[2][4];
    #pragma unroll
    for (int i=0;i<2;i++)
      #pragma unroll
      for (int j=0;j<4;j++) acc[i][j] = (f4v){0.f,0.f,0.f,0.f};

    for (int kt=0; kt<Kd; kt+=64){
        #pragma unroll
        for (int e=0;e<4;e++){
            int idx = tid + e*256;            // 0..1023
            int r = idx >> 3, s = idx & 7;
            *reinterpret_cast<bf8v*>(&As[r*LDK + s*8]) =
                *reinterpret_cast<const bf8v*>(A + (size_t)(rowBase+r)*Kd + kt + s*8);
        }
        #pragma unroll
        for (int e=0;e<2;e++){
            int idx = tid + e*256;            // 0..511
            int r = idx >> 3, s = idx & 7;
            *reinterpret_cast<bf8v*>(&Bs[r*LDK + s*8]) =
                *reinterpret_cast<const bf8v*>(Bt + (size_t)(colBase+r)*Kd + kt + s*8);
        }
        __syncthreads();
        #pragma unroll
        for (int ks=0; ks<2; ks++){
            bf8v a0 = *reinterpret_cast<bf8v*>(&As[(w*32 +      ml)*LDK + ks*32 + quad*8]);
            bf8v a1 = *reinterpret_cast<bf8v*>(&As[(w*32 + 16 + ml)*LDK + ks*32 + quad*8]);
            #pragma unroll
            for (int nt=0; nt<4; nt++){
                bf8v b = *reinterpret_cast<bf8v*>(&Bs[(nt*16+ml)*LDK + ks*32 + quad*8]);
                acc[0][nt] = __builtin_amdgcn_mfma_f32_16x16x32_bf16(a0, b, acc[0][nt], 0,0,0);
                acc[1][nt] = __builtin_amdgcn_mfma_f32_16x16x32_bf16(a1, b, acc[1][nt], 0,0,0);
            }
        }
        __syncthreads();
    }

    #pragma unroll
    for (int mt=0; mt<2; mt++){
        #pragma unroll
        for (int nt=0; nt<4; nt++){
            int col = colBase + nt*16 + ml;
            float bb = bias ? bias[col] : 0.0f;
            #pragma unroll
            for (int r=0;r<4;r++){
                int row = rowBase + w*32 + mt*16 + quad*4 + r;
                float v = acc[mt][nt][r] + bb;
                if (ACT==1) v = geluf(v);
                C[(size_t)row*N + col] = v;
            }
        }
    }
}

// ---------------------------------------------------------------------------
// fp32 -> bf16 flat cast (n % 1024 == 0)
// ---------------------------------------------------------------------------
__launch_bounds__(256)
__global__ void cast_kernel(const float* __restrict__ in, unsigned short* __restrict__ out)
{
    size_t idx = ((size_t)blockIdx.x*256 + threadIdx.x)*4;
    float4 v = *reinterpret_cast<const float4*>(in + idx);
    union { unsigned short u[4]; uint2 q; } o;
    o.u[0]=f2bf(v.x); o.u[1]=f2bf(v.y); o.u[2]=f2bf(v.z); o.u[3]=f2bf(v.w);
    *reinterpret_cast<uint2*>(out + idx) = o.q;
}

// ---------------------------------------------------------------------------
// fp32 [K][N] -> bf16 [N][K] cast + transpose, 64x64 LDS tiles.
// grid (N/64, K/64), 256 threads.
// ---------------------------------------------------------------------------
__launch_bounds__(256)
__global__ void castT_kernel(const float* __restrict__ in, unsigned short* __restrict__ out,
                             int Kd, int N)
{
    __shared__ float t[64][65];
    int k0 = blockIdx.y*64, n0 = blockIdx.x*64;
    int c = threadIdx.x & 63, r4 = threadIdx.x >> 6;
    #pragma unroll
    for (int it=0; it<16; it++){
        int row = it*4 + r4;
        t[row][c] = in[(size_t)(k0+row)*N + n0 + c];
    }
    __syncthreads();
    #pragma unroll
    for (int it=0; it<16; it++){
        int row = it*4 + r4;   // n-dim row
        out[(size_t)(n0+row)*Kd + k0 + c] = f2bf(t[c][row]);
    }
}

// ---------------------------------------------------------------------------
// RMSNorm -> bf16 out: one wave per token (D=128, 2 elems/lane)
// ---------------------------------------------------------------------------
__launch_bounds__(256)
__global__ void rms_bf_kernel(const float* __restrict__ x, const float* __restrict__ w,
                              unsigned short* __restrict__ out)
{
    int tid = threadIdx.x;
    int lane = tid & 63, wv = tid >> 6;
    int token = blockIdx.x*4 + wv;
    const float* xr = x + (size_t)token*DD;
    float v0 = xr[lane], v1 = xr[lane+64];
    float ss = v0*v0 + v1*v1;
    #pragma unroll
    for (int off=32; off>0; off>>=1) ss += __shfl_xor(ss, off);
    float r = rsqrtf(ss*(1.0f/DD) + 1e-5f);
    unsigned short* o = out + (size_t)token*DD;
    o[lane]    = f2bf(v0*r*w[lane]);
    o[lane+64] = f2bf(v1*r*w[lane+64]);
}

// ---------------------------------------------------------------------------
// Depthwise causal conv (K=4) + bias + silu.
// ---------------------------------------------------------------------------
__launch_bounds__(256)
__global__ void conv_kernel(const float* __restrict__ hg, const float* __restrict__ cw,
                            const float* __restrict__ cb, float* __restrict__ hc)
{
    int idx = blockIdx.x*256 + threadIdx.x;
    int i = idx & (II-1);
    int m = idx >> 8;
    int s = m & (SQ-1);
    const float* w = cw + i*KKs;
    float a = cb[i];
    #pragma unroll
    for (int k=0;k<KKs;k++){
        int ssrc = s + k - (KKs-1);
        if (ssrc >= 0) a += hg[(size_t)(m + k - (KKs-1))*(2*II) + i] * w[k];
    }
    hc[idx] = siluf(a);
}

// ---------------------------------------------------------------------------
// Per-token x_proj (I->40) then dt_proj (8->I) + softplus.
// ---------------------------------------------------------------------------
__launch_bounds__(64)
__global__ void xproj_dt_kernel(const float* __restrict__ hconv, const float* __restrict__ xpw,
                                const float* __restrict__ dtw, const float* __restrict__ dtbv,
                                float* __restrict__ dt_out, float* __restrict__ bc)
{
    __shared__ float hrow[II];
    __shared__ float ssm[RRs + 2*NNs];
    int m = blockIdx.x, tid = threadIdx.x;
    for (int t=tid; t<II; t+=64) hrow[t] = hconv[(size_t)m*II + t];
    __syncthreads();
    if (tid < 40){
        float a = 0.0f;
        for (int k=0;k<II;k++) a += hrow[k]*xpw[k*40 + tid];
        ssm[tid] = a;
    }
    __syncthreads();
    if (tid < 32) bc[(size_t)m*32 + tid] = ssm[8 + tid];
    for (int ii=tid; ii<II; ii+=64){
        float a = dtbv[ii];
        #pragma unroll
        for (int r=0;r<RRs;r++) a += ssm[r]*dtw[r*II + ii];
        dt_out[(size_t)m*II + ii] = softplusf(a);
    }
}

// ---------------------------------------------------------------------------
// Selective scan. Grid = B*8, block 64: (i_local 32) x (n-half 2), 8 states/thread.
// ---------------------------------------------------------------------------
__launch_bounds__(64)
__global__ void scan_kernel(const float* __restrict__ dtp, const float* __restrict__ bc,
                            const float* __restrict__ hconv, const float* __restrict__ hg,
                            const float* __restrict__ A_log, const float* __restrict__ D_par,
                            float* __restrict__ y)
{
    int b = blockIdx.x >> 3, chunk = blockIdx.x & 7;
    int tid = threadIdx.x;
    int il = tid & 31, nh = tid >> 5;
    int i = chunk*32 + il;
    const float* al = A_log + i*NNs + nh*8;
    float A2[8];
    #pragma unroll
    for (int j=0;j<8;j++) A2[j] = -__expf(al[j]) * 1.44269504f;
    float carry[8];
    #pragma unroll
    for (int j=0;j<8;j++) carry[j]=0.0f;
    const float dpi = D_par[i];
    const int m0 = b*SQ;
    for (int s=0; s<SQ; s++){
        int m = m0 + s;
        float dtv = dtp[(size_t)m*II + i];
        float hv  = hconv[(size_t)m*II + i];
        float gv  = hg[(size_t)m*(2*II) + II + i];
        const float4* bcrow = reinterpret_cast<const float4*>(bc + (size_t)m*32);
        float4 b0 = bcrow[nh*2],   b1 = bcrow[nh*2+1];
        float4 c0 = bcrow[4+nh*2], c1 = bcrow[5+nh*2];
        float Bm[8] = {b0.x,b0.y,b0.z,b0.w,b1.x,b1.y,b1.z,b1.w};
        float Cm[8] = {c0.x,c0.y,c0.z,c0.w,c1.x,c1.y,c1.z,c1.w};
        float du = dtv*hv;
        float acc = 0.0f;
        #pragma unroll
        for (int j=0;j<8;j++){
            float dA = exp2f(dtv*A2[j]);
            carry[j] = carry[j]*dA + du*Bm[j];
            acc += carry[j]*Cm[j];
        }
        acc += __shfl_xor(acc, 32);
        if (nh == 0){
            float yv = (acc + hv*dpi) * siluf(gv);
            y[(size_t)m*II + i] = yv;
        }
    }
}

// ---------------------------------------------------------------------------
// Head per batch + KL.
// ---------------------------------------------------------------------------
__launch_bounds__(128)
__global__ void head_kernel(const float* __restrict__ x, const float* __restrict__ normf,
                            const float* __restrict__ mu_w, const float* __restrict__ mu_b,
                            const float* __restrict__ lv_w, const float* __restrict__ lv_b,
                            const float* __restrict__ eps, const float* __restrict__ h1_w,
                            const float* __restrict__ h1_b, const float* __restrict__ h2_w,
                            const float* __restrict__ h2_b, float* __restrict__ out,
                            float* __restrict__ klacc)
{
    __shared__ float lasts[DD];
    __shared__ float zs[DD];
    __shared__ float hr[256];
    __shared__ float red[2];
    int b = blockIdx.x, d = threadIdx.x;
    int lane = d & 63, wv = d >> 6;
    float xv = x[((size_t)(b*SQ + SQ-1))*DD + d];
    float ss = xv*xv;
    #pragma unroll
    for (int off=32; off>0; off>>=1) ss += __shfl_xor(ss, off);
    if (lane==0) red[wv] = ss;
    __syncthreads();
    float tot = red[0] + red[1];
    float last = xv * rsqrtf(tot*(1.0f/DD) + 1e-5f) * normf[d];
    lasts[d] = last;
    __syncthreads();
    float mu = mu_b[d], lv = lv_b[d];
    for (int j=0;j<DD;j++){
        float lj = lasts[j];
        mu += lj*mu_w[j*DD + d];
        lv += lj*lv_w[j*DD + d];
    }
    float z = mu + eps[b*ZZs + d]*__expf(0.5f*lv);
    zs[d] = z;
    float klp = 1.0f + lv - mu*mu - __expf(lv);
    #pragma unroll
    for (int off=32; off>0; off>>=1) klp += __shfl_xor(klp, off);
    if (lane==0) red[wv] = klp;
    __syncthreads();
    if (d==0) atomicAdd(klacc, red[0]+red[1]);
    for (int o=d; o<256; o+=128){
        float a = h1_b[o];
        for (int j=0;j<DD;j++) a += zs[j]*h1_w[j*256 + o];
        hr[o] = fmaxf(a, 0.0f);
    }
    __syncthreads();
    if (d < 40){
        float a = h2_b[d];
        for (int k=0;k<256;k++) a += hr[k]*h2_w[k*40 + d];
        out[b*(FUTs*2) + d] = a;
    }
}

__global__ void kl_final_kernel(const float* __restrict__ klacc, float* __restrict__ out)
{
    out[0] = -0.5f * klacc[0] * (1.0f/(BQ*ZZs));
}

// ---------------------------------------------------------------------------
extern "C" void kernel_launch(void* const* d_in, const int* in_sizes, int n_in,
                              void* d_out, int out_size, void* d_ws, size_t ws_size,
                              hipStream_t stream)
{
    const float* x_cam     = (const float*)d_in[0];
    const float* x_ego     = (const float*)d_in[1];
    const float* vib_eps   = (const float*)d_in[2];
    const float* vis_w1    = (const float*)d_in[3];
    const float* vis_b1    = (const float*)d_in[4];
    const float* vis_w2    = (const float*)d_in[5];
    const float* vis_b2    = (const float*)d_in[6];
    const float* ego_w     = (const float*)d_in[7];
    const float* ego_b     = (const float*)d_in[8];
    const float* fus_w     = (const float*)d_in[9];
    const float* fus_b     = (const float*)d_in[10];
    const float* norm_w    = (const float*)d_in[11];
    const float* in_proj_w = (const float*)d_in[12];
    const float* conv_w    = (const float*)d_in[13];
    const float* conv_b    = (const float*)d_in[14];
    const float* x_proj_w  = (const float*)d_in[15];
    const float* dt_proj_w = (const float*)d_in[16];
    const float* dt_proj_b = (const float*)d_in[17];
    const float* A_log     = (const float*)d_in[18];
    const float* D_par     = (const float*)d_in[19];
    const float* out_proj_w= (const float*)d_in[20];
    const float* normf_w   = (const float*)d_in[21];
    const float* mu_w      = (const float*)d_in[22];
    const float* mu_b      = (const float*)d_in[23];
    const float* lv_w      = (const float*)d_in[24];
    const float* lv_b      = (const float*)d_in[25];
    const float* h1_w      = (const float*)d_in[26];
    const float* h1_b      = (const float*)d_in[27];
    const float* h2_w      = (const float*)d_in[28];
    const float* h2_b      = (const float*)d_in[29];

    float* ws = (float*)d_ws;

    // ws_size decides whether we can afford the 134 MB bf16 copy of x_cam.
    // (constant across calls -> graph-capture safe)
    const size_t ABF_FLOATS = 33554432;            // 8192*8192 bf16 in float slots
    // big layout offsets (floats)
    const size_t o_v1g  = 0;                       // 8192*512 (aliases hg)
    const size_t o_cat  = 4194304;                 // 8192*256 (aliases hconv)
    const size_t o_xbuf = 6291456;                 // 8192*128
    const size_t o_w1t  = 7340032;                 // 512*8192 bf16 = 2,097,152 slots
    const size_t o_wipt = 9437184;                 // 4*512*128 bf16 = 131,072 slots
    const size_t o_xnbf = 9568256;                 // 8192*128 bf16 = 262,144 slots
    const size_t o_kl   = 9830400;                 // 16 slots
    const size_t o_dyn  = 9830416;                 // union: Abf | mamba bufs
    const size_t NEED_BIG = (o_dyn + ABF_FLOATS) * 4 + 4096;
    const bool big = (ws_size >= NEED_BIG);

    float* v1g   = ws + o_v1g;
    float* hg    = v1g;
    float* cat   = ws + o_cat;
    float* hconv = cat;
    float* xbuf  = ws + o_xbuf;
    unsigned short* wipt = (unsigned short*)(ws + o_wipt);
    unsigned short* xnbf = (unsigned short*)(ws + o_xnbf);
    float* klacc;
    float *dtws, *bcws, *ybuf;
    unsigned short* w1t = (unsigned short*)(ws + o_w1t);
    unsigned short* abf = (unsigned short*)(ws + o_dyn);

    if (big){
        klacc = ws + o_kl;
        dtws  = ws + o_dyn;
        bcws  = dtws + 2097152;
        ybuf  = bcws + 262144;
    } else {
        // compact (round-1-sized) layout, fp32 GEMM1
        dtws  = ws + 7340032;
        bcws  = dtws + 2097152;
        ybuf  = bcws + 262144;
        // wipt/xnbf re-point into compact tail
        wipt  = (unsigned short*)(ws + 11796480);
        xnbf  = (unsigned short*)(ws + 11927552);
        klacc = ws + 12189696;
    }

    hipMemsetAsync(klacc, 0, sizeof(float), stream);

    // ---- weight casts (bf16 + transpose to [N][K]) ----
    for (int l=0; l<LLs; l++)
        castT_kernel<<<dim3(512/64, 128/64), 256, 0, stream>>>(
            in_proj_w + (size_t)l*DD*2*II, wipt + (size_t)l*2*II*DD, DD, 2*II);

    if (big){
        castT_kernel<<<dim3(512/64, 8192/64), 256, 0, stream>>>(vis_w1, w1t, 8192, 512);
        cast_kernel<<<(MTOK*8192/4)/256, 256, 0, stream>>>(x_cam, abf);
        // 1) vision GEMM1 via MFMA: gelu(A @ W1 + b1)
        gemm_bf16_kernel<1><<<dim3(512/64, 8192/128), 256, 0, stream>>>(
            abf, w1t, vis_b1, v1g, MTOK, 512, 8192);
    } else {
        gemm_kernel<128,128,1,0><<<dim3(512/128, 8192/128), 256, 0, stream>>>(
            x_cam, vis_w1, vis_b1, v1g, MTOK, 512, 8192, 8192, 512);
    }

    // 2) v2 = v1g @ vis_w2 + b2 -> cat[:, :128]
    gemm_kernel<64,64,0,0><<<dim3(2, 128), 256, 0, stream>>>(
        v1g, vis_w2, vis_b2, cat, MTOK, 128, 512, 512, 256);
    // 3) e = x_ego @ ego_w + b -> cat[:, 128:]
    gemm_kernel<64,64,0,0><<<dim3(2, 128), 256, 0, stream>>>(
        x_ego, ego_w, ego_b, cat + 128, MTOK, 128, 64, 64, 256);
    // 4) fused = gelu(cat @ fus_w + fus_b) -> xbuf
    gemm_kernel<64,64,1,0><<<dim3(2, 128), 256, 0, stream>>>(
        cat, fus_w, fus_b, xbuf, MTOK, 128, 256, 256, 128);

    for (int l=0; l<LLs; l++){
        rms_bf_kernel<<<MTOK/4, 256, 0, stream>>>(xbuf, norm_w + l*DD, xnbf);
        gemm_bf16_kernel<0><<<dim3(512/64, 8192/128), 256, 0, stream>>>(
            xnbf, wipt + (size_t)l*2*II*DD, nullptr, hg, MTOK, 2*II, DD);
        conv_kernel<<<MTOK*II/256, 256, 0, stream>>>(
            hg, conv_w + (size_t)l*II*KKs, conv_b + (size_t)l*II, hconv);
        xproj_dt_kernel<<<MTOK, 64, 0, stream>>>(
            hconv, x_proj_w + (size_t)l*II*40, dt_proj_w + (size_t)l*RRs*II,
            dt_proj_b + (size_t)l*II, dtws, bcws);
        scan_kernel<<<BQ*8, 64, 0, stream>>>(
            dtws, bcws, hconv, hg, A_log + (size_t)l*II*NNs, D_par + (size_t)l*II, ybuf);
        gemm_kernel<64,64,0,1><<<dim3(2, 128), 256, 0, stream>>>(
            ybuf, out_proj_w + (size_t)l*II*DD, nullptr, xbuf, MTOK, DD, II, II, DD);
    }

    head_kernel<<<BQ, 128, 0, stream>>>(
        xbuf, normf_w, mu_w, mu_b, lv_w, lv_b, vib_eps,
        h1_w, h1_b, h2_w, h2_b, (float*)d_out, klacc);
    kl_final_kernel<<<1, 1, 0, stream>>>(klacc, (float*)d_out + 1280);
}

// Round 4
// 1896.026 us; speedup vs baseline: 1.3740x; 1.0328x over previous
//
#include <hip/hip_runtime.h>
#include <hip/hip_bf16.h>
#include <math.h>

#define BQ 32
#define SQ 256
#define MTOK 8192       // B*S
#define DD 128
#define II 256
#define NNs 16
#define RRs 8
#define KKs 4
#define LLs 4
#define ZZs 128
#define FUTs 20

typedef __attribute__((ext_vector_type(8))) short bf8v;   // 8 bf16 (4 VGPRs)
typedef __attribute__((ext_vector_type(4))) float f4v;    // 4 fp32 acc

__device__ __forceinline__ float geluf(float x){ return 0.5f*x*(1.0f+erff(x*0.70710678118654752f)); }
__device__ __forceinline__ float siluf(float x){ return x/(1.0f+__expf(-x)); }
__device__ __forceinline__ float softplusf(float x){ return fmaxf(x,0.0f)+log1pf(__expf(-fabsf(x))); }
__device__ __forceinline__ unsigned short f2bf(float x){
    __hip_bfloat16 h = __float2bfloat16(x);
    return *reinterpret_cast<unsigned short*>(&h);
}

// ---------------------------------------------------------------------------
// bf16 MFMA GEMM: C[M,N] = act(A[M,K] @ Bt[N,K]^T + bias) (+C if ADD)
// A is fp32 (cast in staging) or bf16 per AT. BM=128, BN=64, BK=64.
// Grid launched as dim3(M/128, N/64): blockIdx.x = M-tile so N-tile blocks
// sharing A rows have flat ids differing by gridDim.x (multiple of 8) ->
// same XCD under round-robin dispatch -> A fetched once per XCD.
// 4 waves; wave w covers rows w*32..+32 (2 m-tiles) x 64 cols (4 n-tiles).
// LDS rows padded to 72 bf16. Requires M%128==0, N%64==0, K%64==0.
// ---------------------------------------------------------------------------
template<int ACT,int ADD,typename AT>
__launch_bounds__(256,2)
__global__ void gemm_bf16_kernel(const AT* __restrict__ A,
                                 const unsigned short* __restrict__ Bt,
                                 const float* __restrict__ bias,
                                 float* __restrict__ C,
                                 int M, int N, int Kd, int ldc)
{
    constexpr int LDK = 72;
    __shared__ unsigned short As[128*LDK];
    __shared__ unsigned short Bs[64*LDK];
    const int tid = threadIdx.x;
    const int w = tid >> 6, lane = tid & 63;
    const int ml = lane & 15, quad = lane >> 4;
    const int rowBase = blockIdx.x * 128, colBase = blockIdx.y * 64;

    f4v acc[2][4];
    #pragma unroll
    for (int i=0;i<2;i++)
      #pragma unroll
      for (int j=0;j<4;j++) acc[i][j] = (f4v){0.f,0.f,0.f,0.f};

    for (int kt=0; kt<Kd; kt+=64){
        #pragma unroll
        for (int e=0;e<4;e++){
            int idx = tid + e*256;            // 0..1023
            int r = idx >> 3, s = idx & 7;
            if constexpr (sizeof(AT)==2){
                *reinterpret_cast<bf8v*>(&As[r*LDK + s*8]) =
                    *reinterpret_cast<const bf8v*>((const unsigned short*)A + (size_t)(rowBase+r)*Kd + kt + s*8);
            } else {
                const float* ap = (const float*)A + (size_t)(rowBase+r)*Kd + kt + s*8;
                float4 v0 = *reinterpret_cast<const float4*>(ap);
                float4 v1 = *reinterpret_cast<const float4*>(ap+4);
                union { unsigned short u[8]; bf8v v; } o;
                o.u[0]=f2bf(v0.x); o.u[1]=f2bf(v0.y); o.u[2]=f2bf(v0.z); o.u[3]=f2bf(v0.w);
                o.u[4]=f2bf(v1.x); o.u[5]=f2bf(v1.y); o.u[6]=f2bf(v1.z); o.u[7]=f2bf(v1.w);
                *reinterpret_cast<bf8v*>(&As[r*LDK + s*8]) = o.v;
            }
        }
        #pragma unroll
        for (int e=0;e<2;e++){
            int idx = tid + e*256;            // 0..511
            int r = idx >> 3, s = idx & 7;
            *reinterpret_cast<bf8v*>(&Bs[r*LDK + s*8]) =
                *reinterpret_cast<const bf8v*>(Bt + (size_t)(colBase+r)*Kd + kt + s*8);
        }
        __syncthreads();
        #pragma unroll
        for (int ks=0; ks<2; ks++){
            bf8v a0 = *reinterpret_cast<bf8v*>(&As[(w*32 +      ml)*LDK + ks*32 + quad*8]);
            bf8v a1 = *reinterpret_cast<bf8v*>(&As[(w*32 + 16 + ml)*LDK + ks*32 + quad*8]);
            #pragma unroll
            for (int nt=0; nt<4; nt++){
                bf8v b = *reinterpret_cast<bf8v*>(&Bs[(nt*16+ml)*LDK + ks*32 + quad*8]);
                acc[0][nt] = __builtin_amdgcn_mfma_f32_16x16x32_bf16(a0, b, acc[0][nt], 0,0,0);
                acc[1][nt] = __builtin_amdgcn_mfma_f32_16x16x32_bf16(a1, b, acc[1][nt], 0,0,0);
            }
        }
        __syncthreads();
    }

    #pragma unroll
    for (int mt=0; mt<2; mt++){
        #pragma unroll
        for (int nt=0; nt<4; nt++){
            int col = colBase + nt*16 + ml;
            float bb = bias ? bias[col] : 0.0f;
            #pragma unroll
            for (int r=0;r<4;r++){
                int row = rowBase + w*32 + mt*16 + quad*4 + r;
                float v = acc[mt][nt][r] + bb;
                if (ACT==1) v = geluf(v);
                float* cp = C + (size_t)row*ldc + col;
                if (ADD) v += *cp;
                *cp = v;
            }
        }
    }
}

// ---------------------------------------------------------------------------
// fp32 [K][N] -> bf16 [N][K] cast + transpose, 64x64 LDS tiles.
// grid (N/64, K/64), 256 threads.
// ---------------------------------------------------------------------------
__launch_bounds__(256)
__global__ void castT_kernel(const float* __restrict__ in, unsigned short* __restrict__ out,
                             int Kd, int N)
{
    __shared__ float t[64][65];
    int k0 = blockIdx.y*64, n0 = blockIdx.x*64;
    int c = threadIdx.x & 63, r4 = threadIdx.x >> 6;
    #pragma unroll
    for (int it=0; it<16; it++){
        int row = it*4 + r4;
        t[row][c] = in[(size_t)(k0+row)*N + n0 + c];
    }
    __syncthreads();
    #pragma unroll
    for (int it=0; it<16; it++){
        int row = it*4 + r4;   // n-dim row
        out[(size_t)(n0+row)*Kd + k0 + c] = f2bf(t[c][row]);
    }
}

// ---------------------------------------------------------------------------
// RMSNorm -> bf16 out: one wave per token (D=128, 2 elems/lane)
// ---------------------------------------------------------------------------
__launch_bounds__(256)
__global__ void rms_bf_kernel(const float* __restrict__ x, const float* __restrict__ w,
                              unsigned short* __restrict__ out)
{
    int tid = threadIdx.x;
    int lane = tid & 63, wv = tid >> 6;
    int token = blockIdx.x*4 + wv;
    const float* xr = x + (size_t)token*DD;
    float v0 = xr[lane], v1 = xr[lane+64];
    float ss = v0*v0 + v1*v1;
    #pragma unroll
    for (int off=32; off>0; off>>=1) ss += __shfl_xor(ss, off);
    float r = rsqrtf(ss*(1.0f/DD) + 1e-5f);
    unsigned short* o = out + (size_t)token*DD;
    o[lane]    = f2bf(v0*r*w[lane]);
    o[lane+64] = f2bf(v1*r*w[lane+64]);
}

// ---------------------------------------------------------------------------
// Depthwise causal conv (K=4) + bias + silu.
// ---------------------------------------------------------------------------
__launch_bounds__(256)
__global__ void conv_kernel(const float* __restrict__ hg, const float* __restrict__ cw,
                            const float* __restrict__ cb, float* __restrict__ hc)
{
    int idx = blockIdx.x*256 + threadIdx.x;
    int i = idx & (II-1);
    int m = idx >> 8;
    int s = m & (SQ-1);
    const float* w = cw + i*KKs;
    float a = cb[i];
    #pragma unroll
    for (int k=0;k<KKs;k++){
        int ssrc = s + k - (KKs-1);
        if (ssrc >= 0) a += hg[(size_t)(m + k - (KKs-1))*(2*II) + i] * w[k];
    }
    hc[idx] = siluf(a);
}

// ---------------------------------------------------------------------------
// Per-token x_proj (I->40) then dt_proj (8->I) + softplus.
// ---------------------------------------------------------------------------
__launch_bounds__(64)
__global__ void xproj_dt_kernel(const float* __restrict__ hconv, const float* __restrict__ xpw,
                                const float* __restrict__ dtw, const float* __restrict__ dtbv,
                                float* __restrict__ dt_out, float* __restrict__ bc)
{
    __shared__ float hrow[II];
    __shared__ float ssm[RRs + 2*NNs];
    int m = blockIdx.x, tid = threadIdx.x;
    for (int t=tid; t<II; t+=64) hrow[t] = hconv[(size_t)m*II + t];
    __syncthreads();
    if (tid < 40){
        float a = 0.0f;
        for (int k=0;k<II;k++) a += hrow[k]*xpw[k*40 + tid];
        ssm[tid] = a;
    }
    __syncthreads();
    if (tid < 32) bc[(size_t)m*32 + tid] = ssm[8 + tid];
    for (int ii=tid; ii<II; ii+=64){
        float a = dtbv[ii];
        #pragma unroll
        for (int r=0;r<RRs;r++) a += ssm[r]*dtw[r*II + ii];
        dt_out[(size_t)m*II + ii] = softplusf(a);
    }
}

// ---------------------------------------------------------------------------
// Selective scan, thread per (i, n). Grid = B*16 (i-chunks of 16), block 256:
// lane = n(4 bits) | i_local(2 bits), wave covers 4 i x 16 n.
// Shuffle-reduce over the 16 n-lanes, n==0 lane writes y.
// ---------------------------------------------------------------------------
__launch_bounds__(256)
__global__ void scan_kernel(const float* __restrict__ dtp, const float* __restrict__ bc,
                            const float* __restrict__ hconv, const float* __restrict__ hg,
                            const float* __restrict__ A_log, const float* __restrict__ D_par,
                            float* __restrict__ y)
{
    int b = blockIdx.x >> 4, chunk = blockIdx.x & 15;
    int tid = threadIdx.x;
    int n = tid & 15;
    int i = chunk*16 + (tid >> 4);
    float A2 = -__expf(A_log[i*NNs + n]) * 1.44269504f;   // A*log2(e)
    float carry = 0.0f;
    const float dpi = D_par[i];
    const int m0 = b*SQ;
    #pragma unroll 4
    for (int s=0; s<SQ; s++){
        int m = m0 + s;
        float dtv = dtp[(size_t)m*II + i];
        float hv  = hconv[(size_t)m*II + i];
        float Bn  = bc[(size_t)m*32 + n];
        float Cn  = bc[(size_t)m*32 + 16 + n];
        float dA = exp2f(dtv*A2);
        carry = carry*dA + dtv*hv*Bn;
        float acc = carry*Cn;
        acc += __shfl_xor(acc, 1);
        acc += __shfl_xor(acc, 2);
        acc += __shfl_xor(acc, 4);
        acc += __shfl_xor(acc, 8);
        if (n == 0){
            float gv = hg[(size_t)m*(2*II) + II + i];
            y[(size_t)m*II + i] = (acc + hv*dpi) * siluf(gv);
        }
    }
}

// ---------------------------------------------------------------------------
// Head per batch + KL.
// ---------------------------------------------------------------------------
__launch_bounds__(128)
__global__ void head_kernel(const float* __restrict__ x, const float* __restrict__ normf,
                            const float* __restrict__ mu_w, const float* __restrict__ mu_b,
                            const float* __restrict__ lv_w, const float* __restrict__ lv_b,
                            const float* __restrict__ eps, const float* __restrict__ h1_w,
                            const float* __restrict__ h1_b, const float* __restrict__ h2_w,
                            const float* __restrict__ h2_b, float* __restrict__ out,
                            float* __restrict__ klacc)
{
    __shared__ float lasts[DD];
    __shared__ float zs[DD];
    __shared__ float hr[256];
    __shared__ float red[2];
    int b = blockIdx.x, d = threadIdx.x;
    int lane = d & 63, wv = d >> 6;
    float xv = x[((size_t)(b*SQ + SQ-1))*DD + d];
    float ss = xv*xv;
    #pragma unroll
    for (int off=32; off>0; off>>=1) ss += __shfl_xor(ss, off);
    if (lane==0) red[wv] = ss;
    __syncthreads();
    float tot = red[0] + red[1];
    float last = xv * rsqrtf(tot*(1.0f/DD) + 1e-5f) * normf[d];
    lasts[d] = last;
    __syncthreads();
    float mu = mu_b[d], lv = lv_b[d];
    for (int j=0;j<DD;j++){
        float lj = lasts[j];
        mu += lj*mu_w[j*DD + d];
        lv += lj*lv_w[j*DD + d];
    }
    float z = mu + eps[b*ZZs + d]*__expf(0.5f*lv);
    zs[d] = z;
    float klp = 1.0f + lv - mu*mu - __expf(lv);
    #pragma unroll
    for (int off=32; off>0; off>>=1) klp += __shfl_xor(klp, off);
    if (lane==0) red[wv] = klp;
    __syncthreads();
    if (d==0) atomicAdd(klacc, red[0]+red[1]);
    for (int o=d; o<256; o+=128){
        float a = h1_b[o];
        for (int j=0;j<DD;j++) a += zs[j]*h1_w[j*256 + o];
        hr[o] = fmaxf(a, 0.0f);
    }
    __syncthreads();
    if (d < 40){
        float a = h2_b[d];
        for (int k=0;k<256;k++) a += hr[k]*h2_w[k*40 + d];
        out[b*(FUTs*2) + d] = a;
    }
}

__global__ void kl_final_kernel(const float* __restrict__ klacc, float* __restrict__ out)
{
    out[0] = -0.5f * klacc[0] * (1.0f/(BQ*ZZs));
}

// ---------------------------------------------------------------------------
extern "C" void kernel_launch(void* const* d_in, const int* in_sizes, int n_in,
                              void* d_out, int out_size, void* d_ws, size_t ws_size,
                              hipStream_t stream)
{
    const float* x_cam     = (const float*)d_in[0];
    const float* x_ego     = (const float*)d_in[1];
    const float* vib_eps   = (const float*)d_in[2];
    const float* vis_w1    = (const float*)d_in[3];
    const float* vis_b1    = (const float*)d_in[4];
    const float* vis_w2    = (const float*)d_in[5];
    const float* vis_b2    = (const float*)d_in[6];
    const float* ego_w     = (const float*)d_in[7];
    const float* ego_b     = (const float*)d_in[8];
    const float* fus_w     = (const float*)d_in[9];
    const float* fus_b     = (const float*)d_in[10];
    const float* norm_w    = (const float*)d_in[11];
    const float* in_proj_w = (const float*)d_in[12];
    const float* conv_w    = (const float*)d_in[13];
    const float* conv_b    = (const float*)d_in[14];
    const float* x_proj_w  = (const float*)d_in[15];
    const float* dt_proj_w = (const float*)d_in[16];
    const float* dt_proj_b = (const float*)d_in[17];
    const float* A_log     = (const float*)d_in[18];
    const float* D_par     = (const float*)d_in[19];
    const float* out_proj_w= (const float*)d_in[20];
    const float* normf_w   = (const float*)d_in[21];
    const float* mu_w      = (const float*)d_in[22];
    const float* mu_b      = (const float*)d_in[23];
    const float* lv_w      = (const float*)d_in[24];
    const float* lv_b      = (const float*)d_in[25];
    const float* h1_w      = (const float*)d_in[26];
    const float* h1_b      = (const float*)d_in[27];
    const float* h2_w      = (const float*)d_in[28];
    const float* h2_b      = (const float*)d_in[29];

    float* ws = (float*)d_ws;
    // layout (float offsets) — sizes in float slots (bf16 buffers take count/2)
    float* v1g   = ws;                                   // 8192*512 = 4,194,304 (aliases hg)
    float* hg    = v1g;
    float* cat   = ws + 4194304;                         // 8192*256 = 2,097,152 (aliases hconv)
    float* hconv = cat;
    float* xbuf  = ws + 6291456;                         // 8192*128 = 1,048,576
    float* ybuf  = ws + 7340032;                         // 8192*256 = 2,097,152
    float* dtws  = ws + 9437184;                         // 8192*256 = 2,097,152
    float* bcws  = ws + 11534336;                        // 8192*32  =   262,144
    unsigned short* w1t  = (unsigned short*)(ws + 11796480);  // 512*8192 bf16 = 2,097,152 floats
    unsigned short* w2t  = (unsigned short*)(ws + 13893632);  // 128*512  bf16 =    32,768
    unsigned short* egot = (unsigned short*)(ws + 13926400);  // 128*64   bf16 =     4,096
    unsigned short* fust = (unsigned short*)(ws + 13930496);  // 128*256  bf16 =    16,384
    unsigned short* wipt = (unsigned short*)(ws + 13946880);  // 4*512*128 bf16 =  131,072
    unsigned short* wopt = (unsigned short*)(ws + 14077952);  // 4*128*256 bf16 =   65,536
    unsigned short* xnbf = (unsigned short*)(ws + 14143488);  // 8192*128 bf16 =   524,288
    float* klacc = ws + 14667776;                        // 1

    hipMemsetAsync(klacc, 0, sizeof(float), stream);

    // ---- weight casts: bf16 + transpose to [N][K] ----
    castT_kernel<<<dim3(8, 128), 256, 0, stream>>>(vis_w1, w1t, 8192, 512);
    castT_kernel<<<dim3(2, 8),   256, 0, stream>>>(vis_w2, w2t, 512, 128);
    castT_kernel<<<dim3(2, 1),   256, 0, stream>>>(ego_w,  egot, 64, 128);
    castT_kernel<<<dim3(2, 4),   256, 0, stream>>>(fus_w,  fust, 256, 128);
    for (int l=0; l<LLs; l++){
        castT_kernel<<<dim3(8, 2), 256, 0, stream>>>(
            in_proj_w + (size_t)l*DD*2*II, wipt + (size_t)l*2*II*DD, DD, 2*II);
        castT_kernel<<<dim3(2, 4), 256, 0, stream>>>(
            out_proj_w + (size_t)l*II*DD, wopt + (size_t)l*DD*II, II, DD);
    }

    // 1) vision GEMM1: gelu(x_cam @ W1 + b1) -> v1g  (fp32 A cast in staging)
    gemm_bf16_kernel<1,0,float><<<dim3(64, 8), 256, 0, stream>>>(
        x_cam, w1t, vis_b1, v1g, MTOK, 512, 8192, 512);
    // 2) v2 = v1g @ W2 + b2 -> cat[:, :128]
    gemm_bf16_kernel<0,0,float><<<dim3(64, 2), 256, 0, stream>>>(
        v1g, w2t, vis_b2, cat, MTOK, 128, 512, 256);
    // 3) e = x_ego @ ego_w + b -> cat[:, 128:]
    gemm_bf16_kernel<0,0,float><<<dim3(64, 2), 256, 0, stream>>>(
        x_ego, egot, ego_b, cat + 128, MTOK, 128, 64, 256);
    // 4) fused = gelu(cat @ fus_w + b) -> xbuf
    gemm_bf16_kernel<1,0,float><<<dim3(64, 2), 256, 0, stream>>>(
        cat, fust, fus_b, xbuf, MTOK, 128, 256, 128);

    for (int l=0; l<LLs; l++){
        rms_bf_kernel<<<MTOK/4, 256, 0, stream>>>(xbuf, norm_w + l*DD, xnbf);
        gemm_bf16_kernel<0,0,unsigned short><<<dim3(64, 8), 256, 0, stream>>>(
            xnbf, wipt + (size_t)l*2*II*DD, nullptr, hg, MTOK, 2*II, DD, 2*II);
        conv_kernel<<<MTOK*II/256, 256, 0, stream>>>(
            hg, conv_w + (size_t)l*II*KKs, conv_b + (size_t)l*II, hconv);
        xproj_dt_kernel<<<MTOK, 64, 0, stream>>>(
            hconv, x_proj_w + (size_t)l*II*40, dt_proj_w + (size_t)l*RRs*II,
            dt_proj_b + (size_t)l*II, dtws, bcws);
        scan_kernel<<<BQ*16, 256, 0, stream>>>(
            dtws, bcws, hconv, hg, A_log + (size_t)l*II*NNs, D_par + (size_t)l*II, ybuf);
        gemm_bf16_kernel<0,1,float><<<dim3(64, 2), 256, 0, stream>>>(
            ybuf, wopt + (size_t)l*DD*II, nullptr, xbuf, MTOK, DD, II, DD);
    }

    head_kernel<<<BQ, 128, 0, stream>>>(
        xbuf, normf_w, mu_w, mu_b, lv_w, lv_b, vib_eps,
        h1_w, h1_b, h2_w, h2_b, (float*)d_out, klacc);
    kl_final_kernel<<<1, 1, 0, stream>>>(klacc, (float*)d_out + 1280);
}

// Round 5
// 1193.493 us; speedup vs baseline: 2.1828x; 1.5886x over previous
//
#include <hip/hip_runtime.h>
#include <hip/hip_bf16.h>
#include <math.h>

#define BQ 32
#define SQ 256
#define MTOK 8192       // B*S
#define DD 128
#define II 256
#define NNs 16
#define RRs 8
#define KKs 4
#define LLs 4
#define ZZs 128
#define FUTs 20

typedef __attribute__((ext_vector_type(8))) short bf8v;   // 8 bf16 (4 VGPRs)
typedef __attribute__((ext_vector_type(4))) float f4v;    // 4 fp32 acc

__device__ __forceinline__ float geluf(float x){ return 0.5f*x*(1.0f+erff(x*0.70710678118654752f)); }
__device__ __forceinline__ float siluf(float x){ return x/(1.0f+__expf(-x)); }
__device__ __forceinline__ float softplusf(float x){ return fmaxf(x,0.0f)+log1pf(__expf(-fabsf(x))); }
__device__ __forceinline__ unsigned short f2bf(float x){
    __hip_bfloat16 h = __float2bfloat16(x);
    return *reinterpret_cast<unsigned short*>(&h);
}

// ---------------------------------------------------------------------------
// bf16 MFMA GEMM, register-prefetch pipelined.
// C[M,N] = act(A[M,K] @ Bt[N,K]^T + bias) (+C if ADD). A fp32 or bf16 per AT.
// OUTBF=1 -> C is bf16 (no ADD). BM=128, BN=64, BK=64.
// Grid dim3(M/128, N/64): blockIdx.x = M-tile -> N-tile blocks sharing A rows
// differ by gridDim.x (mult of 8) in flat id -> same XCD -> A fetched once.
// Pipeline: regs hold tile k+1's global data while MFMAs consume tile k from
// LDS; ds_write of k+1 happens after the tail barrier. Hides VMEM latency
// behind the MFMA+ds_read phase (R4 was latency-bound at MfmaUtil 6%).
// ---------------------------------------------------------------------------
template<int ACT,int ADD,int OUTBF,typename AT>
__launch_bounds__(256,2)
__global__ void gemm_bf16_kernel(const AT* __restrict__ A,
                                 const unsigned short* __restrict__ Bt,
                                 const float* __restrict__ bias,
                                 void* __restrict__ Cv,
                                 int M, int N, int Kd, int ldc)
{
    constexpr int LDK = 72;
    __shared__ unsigned short As[128*LDK];
    __shared__ unsigned short Bs[64*LDK];
    const int tid = threadIdx.x;
    const int w = tid >> 6, lane = tid & 63;
    const int ml = lane & 15, quad = lane >> 4;
    const int rowBase = blockIdx.x * 128, colBase = blockIdx.y * 64;

    f4v acc[2][4];
    #pragma unroll
    for (int i=0;i<2;i++)
      #pragma unroll
      for (int j=0;j<4;j++) acc[i][j] = (f4v){0.f,0.f,0.f,0.f};

    bf8v pa[4], pb[2];
    const int ar = tid >> 3, as8 = (tid & 7) * 8;   // A/B staging row & col

    auto loadTile = [&](int kt){
        #pragma unroll
        for (int e=0;e<4;e++){
            int r = ar + e*32;
            if constexpr (sizeof(AT)==2){
                pa[e] = *reinterpret_cast<const bf8v*>(
                    (const unsigned short*)A + (size_t)(rowBase+r)*Kd + kt + as8);
            } else {
                const float* ap = (const float*)A + (size_t)(rowBase+r)*Kd + kt + as8;
                float4 v0 = *reinterpret_cast<const float4*>(ap);
                float4 v1 = *reinterpret_cast<const float4*>(ap+4);
                union { unsigned short u[8]; bf8v v; } o;
                o.u[0]=f2bf(v0.x); o.u[1]=f2bf(v0.y); o.u[2]=f2bf(v0.z); o.u[3]=f2bf(v0.w);
                o.u[4]=f2bf(v1.x); o.u[5]=f2bf(v1.y); o.u[6]=f2bf(v1.z); o.u[7]=f2bf(v1.w);
                pa[e] = o.v;
            }
        }
        #pragma unroll
        for (int e=0;e<2;e++){
            int r = ar + e*32;
            pb[e] = *reinterpret_cast<const bf8v*>(
                Bt + (size_t)(colBase+r)*Kd + kt + as8);
        }
    };

    loadTile(0);

    for (int kt=0; kt<Kd; kt+=64){
        // commit prefetched tile to LDS
        #pragma unroll
        for (int e=0;e<4;e++) *reinterpret_cast<bf8v*>(&As[(ar+e*32)*LDK + as8]) = pa[e];
        #pragma unroll
        for (int e=0;e<2;e++) *reinterpret_cast<bf8v*>(&Bs[(ar+e*32)*LDK + as8]) = pb[e];
        __syncthreads();
        // issue next tile's loads (fly during MFMA phase)
        if (kt + 64 < Kd) loadTile(kt + 64);
        #pragma unroll
        for (int ks=0; ks<2; ks++){
            bf8v a0 = *reinterpret_cast<bf8v*>(&As[(w*32 +      ml)*LDK + ks*32 + quad*8]);
            bf8v a1 = *reinterpret_cast<bf8v*>(&As[(w*32 + 16 + ml)*LDK + ks*32 + quad*8]);
            #pragma unroll
            for (int nt=0; nt<4; nt++){
                bf8v b = *reinterpret_cast<bf8v*>(&Bs[(nt*16+ml)*LDK + ks*32 + quad*8]);
                acc[0][nt] = __builtin_amdgcn_mfma_f32_16x16x32_bf16(a0, b, acc[0][nt], 0,0,0);
                acc[1][nt] = __builtin_amdgcn_mfma_f32_16x16x32_bf16(a1, b, acc[1][nt], 0,0,0);
            }
        }
        __syncthreads();
    }

    #pragma unroll
    for (int mt=0; mt<2; mt++){
        #pragma unroll
        for (int nt=0; nt<4; nt++){
            int col = colBase + nt*16 + ml;
            float bb = bias ? bias[col] : 0.0f;
            #pragma unroll
            for (int r=0;r<4;r++){
                int row = rowBase + w*32 + mt*16 + quad*4 + r;
                float v = acc[mt][nt][r] + bb;
                if (ACT==1) v = geluf(v);
                if constexpr (OUTBF==1){
                    ((unsigned short*)Cv)[(size_t)row*ldc + col] = f2bf(v);
                } else {
                    float* cp = (float*)Cv + (size_t)row*ldc + col;
                    if (ADD) v += *cp;
                    *cp = v;
                }
            }
        }
    }
}

// ---------------------------------------------------------------------------
// fp32 [K][N] -> bf16 [N][K] cast + transpose, 64x64 LDS tiles.
// ---------------------------------------------------------------------------
__launch_bounds__(256)
__global__ void castT_kernel(const float* __restrict__ in, unsigned short* __restrict__ out,
                             int Kd, int N)
{
    __shared__ float t[64][65];
    int k0 = blockIdx.y*64, n0 = blockIdx.x*64;
    int c = threadIdx.x & 63, r4 = threadIdx.x >> 6;
    #pragma unroll
    for (int it=0; it<16; it++){
        int row = it*4 + r4;
        t[row][c] = in[(size_t)(k0+row)*N + n0 + c];
    }
    __syncthreads();
    #pragma unroll
    for (int it=0; it<16; it++){
        int row = it*4 + r4;   // n-dim row
        out[(size_t)(n0+row)*Kd + k0 + c] = f2bf(t[c][row]);
    }
}

// ---------------------------------------------------------------------------
// RMSNorm -> bf16 out: one wave per token
// ---------------------------------------------------------------------------
__launch_bounds__(256)
__global__ void rms_bf_kernel(const float* __restrict__ x, const float* __restrict__ w,
                              unsigned short* __restrict__ out)
{
    int tid = threadIdx.x;
    int lane = tid & 63, wv = tid >> 6;
    int token = blockIdx.x*4 + wv;
    const float* xr = x + (size_t)token*DD;
    float v0 = xr[lane], v1 = xr[lane+64];
    float ss = v0*v0 + v1*v1;
    #pragma unroll
    for (int off=32; off>0; off>>=1) ss += __shfl_xor(ss, off);
    float r = rsqrtf(ss*(1.0f/DD) + 1e-5f);
    unsigned short* o = out + (size_t)token*DD;
    o[lane]    = f2bf(v0*r*w[lane]);
    o[lane+64] = f2bf(v1*r*w[lane+64]);
}

// ---------------------------------------------------------------------------
// Depthwise causal conv (K=4) + bias + silu. hg fp32 (MTOK,512), h = cols 0..255.
// ---------------------------------------------------------------------------
__launch_bounds__(256)
__global__ void conv_kernel(const float* __restrict__ hg, const float* __restrict__ cw,
                            const float* __restrict__ cb, float* __restrict__ hc)
{
    int idx = blockIdx.x*256 + threadIdx.x;
    int i = idx & (II-1);
    int m = idx >> 8;
    int s = m & (SQ-1);
    const float* w = cw + i*KKs;
    float a = cb[i];
    #pragma unroll
    for (int k=0;k<KKs;k++){
        int ssrc = s + k - (KKs-1);
        if (ssrc >= 0) a += hg[(size_t)(m + k - (KKs-1))*(2*II) + i] * w[k];
    }
    hc[idx] = siluf(a);
}

// ---------------------------------------------------------------------------
// Per-token x_proj (I->40) then dt_proj (8->I) + softplus.
// ---------------------------------------------------------------------------
__launch_bounds__(64)
__global__ void xproj_dt_kernel(const float* __restrict__ hconv, const float* __restrict__ xpw,
                                const float* __restrict__ dtw, const float* __restrict__ dtbv,
                                float* __restrict__ dt_out, float* __restrict__ bc)
{
    __shared__ float hrow[II];
    __shared__ float ssm[RRs + 2*NNs];
    int m = blockIdx.x, tid = threadIdx.x;
    for (int t=tid; t<II; t+=64) hrow[t] = hconv[(size_t)m*II + t];
    __syncthreads();
    if (tid < 40){
        float a = 0.0f;
        #pragma unroll 8
        for (int k=0;k<II;k++) a += hrow[k]*xpw[k*40 + tid];
        ssm[tid] = a;
    }
    __syncthreads();
    if (tid < 32) bc[(size_t)m*32 + tid] = ssm[8 + tid];
    for (int ii=tid; ii<II; ii+=64){
        float a = dtbv[ii];
        #pragma unroll
        for (int r=0;r<RRs;r++) a += ssm[r]*dtw[r*II + ii];
        dt_out[(size_t)m*II + ii] = softplusf(a);
    }
}

// ---------------------------------------------------------------------------
// Selective scan, LDS-chunked. Grid = B*16 (i-chunks of 16), block 256:
// lane n = tid&15, channel il = tid>>4 (16 per block). Inputs staged to LDS
// in 16-step chunks so the serial recurrence never touches global memory.
// Writes y as bf16 (consumer out_proj GEMM casts to bf16 anyway).
// ---------------------------------------------------------------------------
__launch_bounds__(256)
__global__ void scan_kernel(const float* __restrict__ dtp, const float* __restrict__ bc,
                            const float* __restrict__ hconv, const float* __restrict__ hg,
                            const float* __restrict__ A_log, const float* __restrict__ D_par,
                            unsigned short* __restrict__ ybf)
{
    __shared__ float sdt[16][17], shv[16][17], sgv[16][17], sbc[16][33];
    int b = blockIdx.x >> 4, chunk = blockIdx.x & 15;
    int tid = threadIdx.x;
    int n = tid & 15, il = tid >> 4;
    int i = chunk*16 + il;
    float A2 = -__expf(A_log[i*NNs + n]) * 1.44269504f;   // A*log2(e)
    float carry = 0.0f;
    const float dpi = D_par[i];
    const int m0 = b*SQ;
    const int li = tid & 15, ls = tid >> 4;               // loader mapping
    const int gi = chunk*16 + li;
    for (int cs=0; cs<16; cs++){
        __syncthreads();
        int mload = m0 + cs*16 + ls;
        sdt[ls][li] = dtp[(size_t)mload*II + gi];
        shv[ls][li] = hconv[(size_t)mload*II + gi];
        sgv[ls][li] = hg[(size_t)mload*(2*II) + II + gi];
        sbc[ls][li]      = bc[(size_t)mload*32 + li];
        sbc[ls][li + 16] = bc[(size_t)mload*32 + 16 + li];
        __syncthreads();
        #pragma unroll
        for (int s=0; s<16; s++){
            float dtv = sdt[s][il];
            float hv  = shv[s][il];
            float dA  = exp2f(dtv*A2);
            carry = carry*dA + dtv*hv*sbc[s][n];
            float acc = carry*sbc[s][16+n];
            acc += __shfl_xor(acc, 1);
            acc += __shfl_xor(acc, 2);
            acc += __shfl_xor(acc, 4);
            acc += __shfl_xor(acc, 8);
            if (n == 0){
                ybf[(size_t)(m0 + cs*16 + s)*II + i] =
                    f2bf((acc + hv*dpi) * siluf(sgv[s][il]));
            }
        }
    }
}

// ---------------------------------------------------------------------------
// Head per batch + KL.
// ---------------------------------------------------------------------------
__launch_bounds__(128)
__global__ void head_kernel(const float* __restrict__ x, const float* __restrict__ normf,
                            const float* __restrict__ mu_w, const float* __restrict__ mu_b,
                            const float* __restrict__ lv_w, const float* __restrict__ lv_b,
                            const float* __restrict__ eps, const float* __restrict__ h1_w,
                            const float* __restrict__ h1_b, const float* __restrict__ h2_w,
                            const float* __restrict__ h2_b, float* __restrict__ out,
                            float* __restrict__ klacc)
{
    __shared__ float lasts[DD];
    __shared__ float zs[DD];
    __shared__ float hr[256];
    __shared__ float red[2];
    int b = blockIdx.x, d = threadIdx.x;
    int lane = d & 63, wv = d >> 6;
    float xv = x[((size_t)(b*SQ + SQ-1))*DD + d];
    float ss = xv*xv;
    #pragma unroll
    for (int off=32; off>0; off>>=1) ss += __shfl_xor(ss, off);
    if (lane==0) red[wv] = ss;
    __syncthreads();
    float tot = red[0] + red[1];
    float last = xv * rsqrtf(tot*(1.0f/DD) + 1e-5f) * normf[d];
    lasts[d] = last;
    __syncthreads();
    float mu = mu_b[d], lv = lv_b[d];
    for (int j=0;j<DD;j++){
        float lj = lasts[j];
        mu += lj*mu_w[j*DD + d];
        lv += lj*lv_w[j*DD + d];
    }
    float z = mu + eps[b*ZZs + d]*__expf(0.5f*lv);
    zs[d] = z;
    float klp = 1.0f + lv - mu*mu - __expf(lv);
    #pragma unroll
    for (int off=32; off>0; off>>=1) klp += __shfl_xor(klp, off);
    if (lane==0) red[wv] = klp;
    __syncthreads();
    if (d==0) atomicAdd(klacc, red[0]+red[1]);
    for (int o=d; o<256; o+=128){
        float a = h1_b[o];
        for (int j=0;j<DD;j++) a += zs[j]*h1_w[j*256 + o];
        hr[o] = fmaxf(a, 0.0f);
    }
    __syncthreads();
    if (d < 40){
        float a = h2_b[d];
        for (int k=0;k<256;k++) a += hr[k]*h2_w[k*40 + d];
        out[b*(FUTs*2) + d] = a;
    }
}

__global__ void kl_final_kernel(const float* __restrict__ klacc, float* __restrict__ out)
{
    out[0] = -0.5f * klacc[0] * (1.0f/(BQ*ZZs));
}

// ---------------------------------------------------------------------------
extern "C" void kernel_launch(void* const* d_in, const int* in_sizes, int n_in,
                              void* d_out, int out_size, void* d_ws, size_t ws_size,
                              hipStream_t stream)
{
    const float* x_cam     = (const float*)d_in[0];
    const float* x_ego     = (const float*)d_in[1];
    const float* vib_eps   = (const float*)d_in[2];
    const float* vis_w1    = (const float*)d_in[3];
    const float* vis_b1    = (const float*)d_in[4];
    const float* vis_w2    = (const float*)d_in[5];
    const float* vis_b2    = (const float*)d_in[6];
    const float* ego_w     = (const float*)d_in[7];
    const float* ego_b     = (const float*)d_in[8];
    const float* fus_w     = (const float*)d_in[9];
    const float* fus_b     = (const float*)d_in[10];
    const float* norm_w    = (const float*)d_in[11];
    const float* in_proj_w = (const float*)d_in[12];
    const float* conv_w    = (const float*)d_in[13];
    const float* conv_b    = (const float*)d_in[14];
    const float* x_proj_w  = (const float*)d_in[15];
    const float* dt_proj_w = (const float*)d_in[16];
    const float* dt_proj_b = (const float*)d_in[17];
    const float* A_log     = (const float*)d_in[18];
    const float* D_par     = (const float*)d_in[19];
    const float* out_proj_w= (const float*)d_in[20];
    const float* normf_w   = (const float*)d_in[21];
    const float* mu_w      = (const float*)d_in[22];
    const float* mu_b      = (const float*)d_in[23];
    const float* lv_w      = (const float*)d_in[24];
    const float* lv_b      = (const float*)d_in[25];
    const float* h1_w      = (const float*)d_in[26];
    const float* h1_b      = (const float*)d_in[27];
    const float* h2_w      = (const float*)d_in[28];
    const float* h2_b      = (const float*)d_in[29];

    float* ws = (float*)d_ws;
    // layout (float offsets). Aliases: v1g (bf16) lives in hg's slot (hg is
    // only written from layer-loop in_proj, after v1g's last read at GEMM2);
    // catbf (bf16) lives in hconv's slot (hconv first written inside loop).
    float* hg    = ws;                                        // 8192*512 fp32 = 4,194,304
    unsigned short* v1g  = (unsigned short*)hg;               // 8192*512 bf16 (alias)
    float* hconv = ws + 4194304;                              // 8192*256 fp32 = 2,097,152
    unsigned short* catbf = (unsigned short*)hconv;           // 8192*256 bf16 (alias)
    float* xbuf  = ws + 6291456;                              // 8192*128 = 1,048,576
    float* dtws  = ws + 7340032;                              // 8192*256 = 2,097,152
    float* bcws  = ws + 9437184;                              // 8192*32  =   262,144
    unsigned short* ybf  = (unsigned short*)(ws + 9699328);   // 8192*256 bf16 = 1,048,576 floats
    unsigned short* xnbf = (unsigned short*)(ws + 10747904);  // 8192*128 bf16 =   524,288
    unsigned short* w1t  = (unsigned short*)(ws + 11272192);  // 512*8192 bf16 = 2,097,152
    unsigned short* w2t  = (unsigned short*)(ws + 13369344);  // 128*512  bf16 =    32,768
    unsigned short* egot = (unsigned short*)(ws + 13402112);  // 128*64   bf16 =     4,096
    unsigned short* fust = (unsigned short*)(ws + 13406208);  // 128*256  bf16 =    16,384
    unsigned short* wipt = (unsigned short*)(ws + 13422592);  // 4*512*128 bf16 =  131,072
    unsigned short* wopt = (unsigned short*)(ws + 13553664);  // 4*128*256 bf16 =   65,536
    float* klacc = ws + 13619200;

    hipMemsetAsync(klacc, 0, sizeof(float), stream);

    // ---- weight casts: bf16 + transpose to [N][K] ----
    castT_kernel<<<dim3(8, 128), 256, 0, stream>>>(vis_w1, w1t, 8192, 512);
    castT_kernel<<<dim3(2, 8),   256, 0, stream>>>(vis_w2, w2t, 512, 128);
    castT_kernel<<<dim3(2, 1),   256, 0, stream>>>(ego_w,  egot, 64, 128);
    castT_kernel<<<dim3(2, 4),   256, 0, stream>>>(fus_w,  fust, 256, 128);
    for (int l=0; l<LLs; l++){
        castT_kernel<<<dim3(8, 2), 256, 0, stream>>>(
            in_proj_w + (size_t)l*DD*2*II, wipt + (size_t)l*2*II*DD, DD, 2*II);
        castT_kernel<<<dim3(2, 4), 256, 0, stream>>>(
            out_proj_w + (size_t)l*II*DD, wopt + (size_t)l*DD*II, II, DD);
    }

    // 1) vision GEMM1: gelu(x_cam @ W1 + b1) -> v1g (bf16 out)
    gemm_bf16_kernel<1,0,1,float><<<dim3(64, 8), 256, 0, stream>>>(
        x_cam, w1t, vis_b1, v1g, MTOK, 512, 8192, 512);
    // 2) v2 = v1g @ W2 + b2 -> catbf[:, :128] (bf16 out)
    gemm_bf16_kernel<0,0,1,unsigned short><<<dim3(64, 2), 256, 0, stream>>>(
        v1g, w2t, vis_b2, catbf, MTOK, 128, 512, 256);
    // 3) e = x_ego @ ego_w + b -> catbf[:, 128:]
    gemm_bf16_kernel<0,0,1,float><<<dim3(64, 2), 256, 0, stream>>>(
        x_ego, egot, ego_b, catbf + 128, MTOK, 128, 64, 256);
    // 4) fused = gelu(catbf @ fus_w + b) -> xbuf (fp32 residual stream)
    gemm_bf16_kernel<1,0,0,unsigned short><<<dim3(64, 2), 256, 0, stream>>>(
        catbf, fust, fus_b, xbuf, MTOK, 128, 256, 128);

    for (int l=0; l<LLs; l++){
        rms_bf_kernel<<<MTOK/4, 256, 0, stream>>>(xbuf, norm_w + l*DD, xnbf);
        gemm_bf16_kernel<0,0,0,unsigned short><<<dim3(64, 8), 256, 0, stream>>>(
            xnbf, wipt + (size_t)l*2*II*DD, nullptr, hg, MTOK, 2*II, DD, 2*II);
        conv_kernel<<<MTOK*II/256, 256, 0, stream>>>(
            hg, conv_w + (size_t)l*II*KKs, conv_b + (size_t)l*II, hconv);
        xproj_dt_kernel<<<MTOK, 64, 0, stream>>>(
            hconv, x_proj_w + (size_t)l*II*40, dt_proj_w + (size_t)l*RRs*II,
            dt_proj_b + (size_t)l*II, dtws, bcws);
        scan_kernel<<<BQ*16, 256, 0, stream>>>(
            dtws, bcws, hconv, hg, A_log + (size_t)l*II*NNs, D_par + (size_t)l*II, ybf);
        gemm_bf16_kernel<0,1,0,unsigned short><<<dim3(64, 2), 256, 0, stream>>>(
            ybf, wopt + (size_t)l*DD*II, nullptr, xbuf, MTOK, DD, II, DD);
    }

    head_kernel<<<BQ, 128, 0, stream>>>(
        xbuf, normf_w, mu_w, mu_b, lv_w, lv_b, vib_eps,
        h1_w, h1_b, h2_w, h2_b, (float*)d_out, klacc);
    kl_final_kernel<<<1, 1, 0, stream>>>(klacc, (float*)d_out + 1280);
}